// Round 4
// baseline (362.202 us; speedup 1.0000x reference)
//
#include <hip/hip_runtime.h>
#include <hip/hip_bf16.h>

typedef __attribute__((ext_vector_type(4))) float floatx4;
typedef __bf16 bf16x8 __attribute__((ext_vector_type(8)));
typedef unsigned int u32;
typedef unsigned short u16;

typedef __attribute__((address_space(1))) const u32 g_u32;
typedef __attribute__((address_space(3))) u32 l_u32;

__device__ __forceinline__ u16 f32_to_bf16(float f) {
    union { float f; u32 u; } x{f};
    u32 u = x.u;
    u32 r = (u + 0x7fffu + ((u >> 16) & 1u)) >> 16;
    return (u16)r;
}

// ============================================================================
// 8-phase 256x256 GEMM schedule (T1+T2+T3/T4+T5). Verified R2/R3 on qkv:
// 0 bank conflicts, 3 rounds x 38.8 us = 116 us. Staging helper parametrized
// by row stride; LDS dest LINEAR (global_load_lds), T2 swizzle applied on the
// GLOBAL source column + swizzled ds_read (rule #21 both-sides).
// ============================================================================

__device__ __forceinline__ void stage_half_sw(const u16* gbase, int ld, u16* lds_half, int tid) {
    int lane = tid & 63;
    int rsub = lane >> 3;                        // 0..7 row within 8-row slab
    int colsw = ((lane & 7) ^ rsub) << 3;        // swizzled source column (elems)
#pragma unroll
    for (int j = 0; j < 2; ++j) {
        int q = (tid >> 6) * 2 + j;              // 8-row slab index 0..15
        int row = q * 8 + rsub;
        const u16* g = gbase + (long)row * ld + colsw;
        u16* l = lds_half + q * 512 + lane * 8;  // linear: wave base + lane*16B
        __builtin_amdgcn_global_load_lds((g_u32*)g, (l_u32*)l, 16, 0, 0);
    }
}

// The shared 8-phase K=1024 main loop (16 K-tiles of 64, 8 iterations).
// Ab/Bb row strides = lda/ldb. acc[8][4] per thread (wave tile 128x64).
// Hazard schedule identical to the R2-verified qkv kernel — DO NOT EDIT.
#define EIGHT_PHASE_K1024_LOOP(Ab, Bb, lda, ldb)                                       \
    stage_half_sw(Bb,                  ldb, &Bs[0][0],        tid);                    \
    stage_half_sw(Bb + 128 * (ldb),    ldb, &Bs[0][128 * 64], tid);                    \
    stage_half_sw(Ab,                  lda, &As[0][0],        tid);                    \
    stage_half_sw(Ab + 128 * (lda),    lda, &As[0][128 * 64], tid);                    \
    stage_half_sw(Bb + 64,             ldb, &Bs[1][0],        tid);                    \
    stage_half_sw(Bb + 64 + 128 * (ldb), ldb, &Bs[1][128 * 64], tid);                  \
    asm volatile("s_waitcnt vmcnt(4)" ::: "memory");                                   \
    __builtin_amdgcn_sched_barrier(0);                                                 \
    __builtin_amdgcn_s_barrier();                                                      \
    for (int i = 0; i < 8; ++i) {                                                      \
        int t1  = 2 * i + 1;                                                           \
        int tn  = (2 * i + 2 <= 15) ? 2 * i + 2 : 15;                                  \
        int tn1 = (2 * i + 3 <= 15) ? 2 * i + 3 : 15;                                  \
        const u16* gA1 = Ab + t1 * 64;                                                 \
        const u16* gB2 = Bb + tn * 64;                                                 \
        const u16* gA2 = Ab + tn * 64;                                                 \
        const u16* gB3 = Bb + tn1 * 64;                                                \
        bf16x8 bq0[4], bq1[4];                                                         \
        _Pragma("unroll")                                                              \
        for (int half = 0; half < 2; ++half) {                                         \
            _Pragma("unroll")                                                          \
            for (int p = 0; p < 4; ++p) {                                              \
                if (p == 0) {                                                          \
                    _Pragma("unroll")                                                  \
                    for (int ni = 0; ni < 4; ++ni) {                                   \
                        bq0[ni] = *(const bf16x8*)&Bs[half][brow + ni * 1024 + sl0];   \
                        bq1[ni] = *(const bf16x8*)&Bs[half][brow + ni * 1024 + sl1];   \
                    }                                                                  \
                }                                                                      \
                bf16x8 a00 = *(const bf16x8*)&As[half][arow + (2 * p)     * 1024 + sl0]; \
                bf16x8 a01 = *(const bf16x8*)&As[half][arow + (2 * p)     * 1024 + sl1]; \
                bf16x8 a10 = *(const bf16x8*)&As[half][arow + (2 * p + 1) * 1024 + sl0]; \
                bf16x8 a11 = *(const bf16x8*)&As[half][arow + (2 * p + 1) * 1024 + sl1]; \
                int ph = half * 4 + p;                                                 \
                switch (ph) {                                                          \
                    case 0: stage_half_sw(gA1,              lda, &As[1][0],        tid); break; \
                    case 1: stage_half_sw(gA1 + 128 * (lda), lda, &As[1][128 * 64], tid); break; \
                    case 2: stage_half_sw(gB2,              ldb, &Bs[0][0],        tid); break; \
                    case 3: stage_half_sw(gB2 + 128 * (ldb), ldb, &Bs[0][128 * 64], tid); break; \
                    case 4: stage_half_sw(gA2,              lda, &As[0][0],        tid); break; \
                    case 5: stage_half_sw(gA2 + 128 * (lda), lda, &As[0][128 * 64], tid); break; \
                    case 6: stage_half_sw(gB3,              ldb, &Bs[1][0],        tid); break; \
                    case 7: stage_half_sw(gB3 + 128 * (ldb), ldb, &Bs[1][128 * 64], tid); break; \
                }                                                                      \
                __builtin_amdgcn_s_barrier();                                          \
                __builtin_amdgcn_s_setprio(1);                                         \
                int m0 = 2 * p;                                                        \
                _Pragma("unroll")                                                      \
                for (int ni = 0; ni < 4; ++ni) {                                       \
                    acc[m0][ni]     = __builtin_amdgcn_mfma_f32_16x16x32_bf16(a00, bq0[ni], acc[m0][ni],     0, 0, 0); \
                    acc[m0][ni]     = __builtin_amdgcn_mfma_f32_16x16x32_bf16(a01, bq1[ni], acc[m0][ni],     0, 0, 0); \
                    acc[m0 + 1][ni] = __builtin_amdgcn_mfma_f32_16x16x32_bf16(a10, bq0[ni], acc[m0 + 1][ni], 0, 0, 0); \
                    acc[m0 + 1][ni] = __builtin_amdgcn_mfma_f32_16x16x32_bf16(a11, bq1[ni], acc[m0 + 1][ni], 0, 0, 0); \
                }                                                                      \
                __builtin_amdgcn_s_setprio(0);                                         \
                if (p == 3) {                                                          \
                    asm volatile("s_waitcnt vmcnt(4)" ::: "memory");                   \
                    __builtin_amdgcn_sched_barrier(0);                                 \
                }                                                                      \
                __builtin_amdgcn_s_barrier();                                          \
            }                                                                          \
        }                                                                              \
    }                                                                                  \
    asm volatile("s_waitcnt vmcnt(0)" ::: "memory");                                   \
    __builtin_amdgcn_sched_barrier(0);

// ============================================================================
// QKV projection: C = X . Wstk^T. 768 blocks (3 exact rounds). Q,K -> QKi;
// V -> Vt transposed (fused transpose, R3-verified).
// ============================================================================
__global__ __launch_bounds__(512, 2)
void qkv_gemm8(const u16* __restrict__ A, const u16* __restrict__ Bw,
               u16* __restrict__ QKi, u16* __restrict__ Vt)
{
    __shared__ u16 As[2][256 * 64];
    __shared__ u16 Bs[2][256 * 64];

    int bid = blockIdx.x;
    int wg = (bid & 7) * 96 + (bid >> 3);
    int mt = wg / 12, nt = wg - mt * 12;

    int tid = threadIdx.x;
    int lane = tid & 63, wv = tid >> 6;
    int wr = wv >> 2, wc = wv & 3;
    int lrow = lane & 15, quad = lane >> 4;
    int sw = lrow & 7;

    const u16* Ab = A + (long)mt * 256 * 1024;
    const u16* Bb = Bw + (long)nt * 256 * 1024;

    floatx4 acc[8][4] = {};
    const int arow = (wr * 128 + lrow) * 64;
    const int brow = (wc * 64 + lrow) * 64;
    const int sl0 = (quad ^ sw) * 8;
    const int sl1 = ((4 + quad) ^ sw) * 8;

    EIGHT_PHASE_K1024_LOOP(Ab, Bb, 1024, 1024)

    if (nt < 8) {
        long crow0 = (long)mt * 256 + wr * 128 + quad * 4;
        int  ccol0 = nt * 256 + wc * 64 + lrow;
#pragma unroll
        for (int mi = 0; mi < 8; ++mi) {
#pragma unroll
            for (int r = 0; r < 4; ++r) {
                long row = crow0 + mi * 16 + r;
#pragma unroll
                for (int ni = 0; ni < 4; ++ni)
                    QKi[row * 2048 + ccol0 + ni * 16] = f32_to_bf16(acc[mi][ni][r]);
            }
        }
    } else {
        int dv0   = (nt - 8) * 256 + wc * 64 + lrow;
        long tok0 = (long)mt * 256 + wr * 128 + quad * 4;
#pragma unroll
        for (int mi = 0; mi < 8; ++mi) {
#pragma unroll
            for (int ni = 0; ni < 4; ++ni) {
                ushort4 o;
                o.x = f32_to_bf16(acc[mi][ni][0]);
                o.y = f32_to_bf16(acc[mi][ni][1]);
                o.z = f32_to_bf16(acc[mi][ni][2]);
                o.w = f32_to_bf16(acc[mi][ni][3]);
                *(ushort4*)(Vt + (long)(dv0 + ni * 16) * 16384 + tok0 + mi * 16) = o;
            }
        }
    }
}

// ============================================================================
// S kernel, 8-phase 256^2: Ptilde = exp(Q.K^T/32), causal, rowsums.
// Per batch: lower-triangle 8x8 grid of 256^2 tiles = 36; grid 288 = 8 XCD x 36
// (batch-per-XCD: all of a batch's 36 tiles share its 8.4 MB Q/K panel in L2).
// K=1024 -> identical pipeline to qkv. Universal (col>row -> 0) mask is exact:
// never true for mt>nt, correct on diagonal. 2 rounds x ~39 us expected.
// ============================================================================
__global__ __launch_bounds__(512, 2)
void s_gemm8(const u16* __restrict__ QKi, u16* __restrict__ P, float* __restrict__ lsum)
{
    __shared__ u16 As[2][256 * 64];
    __shared__ u16 Bs[2][256 * 64];

    int bid = blockIdx.x;                       // 0..287
    int b  = bid & 7;                           // batch == XCD slot
    int ti = bid >> 3;                          // 0..35 triangle index
    int mt = (int)((__builtin_sqrtf(8.0f * ti + 1.0f) - 1.0f) * 0.5f);
    while ((mt + 1) * (mt + 2) / 2 <= ti) ++mt; // fixup fp rounding
    while (mt * (mt + 1) / 2 > ti) --mt;
    int nt = ti - mt * (mt + 1) / 2;            // nt <= mt

    int tid = threadIdx.x;
    int lane = tid & 63, wv = tid >> 6;
    int wr = wv >> 2, wc = wv & 3;
    int lrow = lane & 15, quad = lane >> 4;
    int sw = lrow & 7;

    const u16* Qb = QKi + (long)b * 2048 * 2048 + (long)mt * 256 * 2048;        // Q rows
    const u16* Kb = QKi + (long)b * 2048 * 2048 + (long)nt * 256 * 2048 + 1024; // K rows
    u16* Pb = P + (long)b * 2048 * 2048;
    float* ls = lsum + b * 2048;

    floatx4 acc[8][4] = {};
    const int arow = (wr * 128 + lrow) * 64;
    const int brow = (wc * 64 + lrow) * 64;
    const int sl0 = (quad ^ sw) * 8;
    const int sl1 = ((4 + quad) ^ sw) * 8;

    EIGHT_PHASE_K1024_LOOP(Qb, Kb, 2048, 2048)

    // Epilogue: e = exp(acc/32) masked; store bf16; rowsum -> atomicAdd.
    int crow0 = mt * 256 + wr * 128 + quad * 4;
    int ccol0 = nt * 256 + wc * 64 + lrow;
#pragma unroll
    for (int mi = 0; mi < 8; ++mi) {
#pragma unroll
        for (int r = 0; r < 4; ++r) {
            int row = crow0 + mi * 16 + r;
            float rs = 0.f;
#pragma unroll
            for (int ni = 0; ni < 4; ++ni) {
                int col = ccol0 + ni * 16;
                float v = acc[mi][ni][r] * 0.03125f;
                float e = (col > row) ? 0.f : __expf(v);
                Pb[(long)row * 2048 + col] = f32_to_bf16(e);
                rs += e;
            }
            rs += __shfl_xor(rs, 1, 16);
            rs += __shfl_xor(rs, 2, 16);
            rs += __shfl_xor(rs, 4, 16);
            rs += __shfl_xor(rs, 8, 16);
            if (lrow == 0) atomicAdd(&ls[row], rs);
        }
    }
}

// ============================================================================
// PV: 128x256 tiles, 512 thr / 8 waves of 64x64, m97 2-barrier loop.
// FROZEN this round (R3 change, no isolated counters yet).
// ============================================================================
__global__ __launch_bounds__(512)
void pv_gemm2(const u16* __restrict__ P, const u16* __restrict__ Vt,
              float* __restrict__ O, const float* __restrict__ lsum)
{
    __shared__ u16 As[128 * 32];   // 8 KB
    __shared__ u16 Bs[256 * 32];   // 16 KB
    int b = blockIdx.x, nt = blockIdx.y, mt = 15 - blockIdx.z;
    const u16* Ab = P  + (long)b * 2048 * 2048 + (long)mt * 128 * 2048;  // lda 2048
    const u16* Bb = Vt + (long)b * 2048 + (long)nt * 256 * 16384;        // ldb 16384
    float* Ob = O + (long)b * 2048 * 1024;
    const float* ls = lsum + b * 2048;
    int nkt = mt * 4 + 4;                         // Keff = (mt+1)*128

    int tid = threadIdx.x, lane = tid & 63, wave = tid >> 6;
    int wr = wave >> 2, wc = wave & 3;
    int lrow = lane & 15, quad = lane >> 4;

    {
        int flat = tid * 8, row = flat >> 5, col = flat & 31;
        __builtin_amdgcn_global_load_lds((g_u32*)(Ab + (long)row * 2048 + col),
                                         (l_u32*)&As[flat], 16, 0, 0);
#pragma unroll
        for (int it = 0; it < 2; ++it) {
            int f2 = it * 4096 + tid * 8, r2 = f2 >> 5, c2 = f2 & 31;
            __builtin_amdgcn_global_load_lds((g_u32*)(Bb + (long)r2 * 16384 + c2),
                                             (l_u32*)&Bs[f2], 16, 0, 0);
        }
    }

    floatx4 acc[4][4] = {};
    const int aoff = (wr * 64 + lrow) * 32 + quad * 8;
    const int boff = (wc * 64 + lrow) * 32 + quad * 8;

    for (int kt = 0; kt < nkt; ++kt) {
        __syncthreads();
        bf16x8 af[4], bfr[4];
#pragma unroll
        for (int i = 0; i < 4; ++i) {
            af[i]  = *(const bf16x8*)&As[aoff + i * 16 * 32];
            bfr[i] = *(const bf16x8*)&Bs[boff + i * 16 * 32];
        }
#pragma unroll
        for (int mi = 0; mi < 4; ++mi)
#pragma unroll
            for (int ni = 0; ni < 4; ++ni)
                acc[mi][ni] = __builtin_amdgcn_mfma_f32_16x16x32_bf16(af[mi], bfr[ni], acc[mi][ni], 0, 0, 0);
        __syncthreads();
        if (kt + 1 < nkt) {
            const u16* An = Ab + (kt + 1) * 32;
            const u16* Bn = Bb + (kt + 1) * 32;
            int flat = tid * 8, row = flat >> 5, col = flat & 31;
            __builtin_amdgcn_global_load_lds((g_u32*)(An + (long)row * 2048 + col),
                                             (l_u32*)&As[flat], 16, 0, 0);
#pragma unroll
            for (int it = 0; it < 2; ++it) {
                int f2 = it * 4096 + tid * 8, r2 = f2 >> 5, c2 = f2 & 31;
                __builtin_amdgcn_global_load_lds((g_u32*)(Bn + (long)r2 * 16384 + c2),
                                                 (l_u32*)&Bs[f2], 16, 0, 0);
            }
        }
    }

    int crow0 = mt * 128 + wr * 64 + quad * 4;
    int ccol0 = nt * 256 + wc * 64 + lrow;
#pragma unroll
    for (int mi = 0; mi < 4; ++mi) {
#pragma unroll
        for (int r = 0; r < 4; ++r) {
            int row = crow0 + mi * 16 + r;
            float linv = 1.0f / ls[row];
#pragma unroll
            for (int ni = 0; ni < 4; ++ni)
                Ob[(long)row * 1024 + ccol0 + ni * 16] = acc[mi][ni][r] * linv;
        }
    }
}

__global__ __launch_bounds__(256)
void cvt_f32_bf16(const float* __restrict__ src, u16* __restrict__ dst, long n)
{
    long idx = ((long)blockIdx.x * 256 + threadIdx.x) << 2;
    if (idx >= n) return;
    float4 f = *(const float4*)(src + idx);
    ushort4 o;
    o.x = f32_to_bf16(f.x); o.y = f32_to_bf16(f.y);
    o.z = f32_to_bf16(f.z); o.w = f32_to_bf16(f.w);
    *(ushort4*)(dst + idx) = o;
}

__global__ __launch_bounds__(256)
void cvt_w3(const float* __restrict__ Wq, const float* __restrict__ Wk,
            const float* __restrict__ Wv, u16* __restrict__ dst)
{
    int which = blockIdx.x >> 10;
    const float* src = which == 0 ? Wq : (which == 1 ? Wk : Wv);
    long base = (long)(blockIdx.x & 1023) * 1024 + threadIdx.x * 4;
    float4 f = *(const float4*)(src + base);
    ushort4 o;
    o.x = f32_to_bf16(f.x); o.y = f32_to_bf16(f.y);
    o.z = f32_to_bf16(f.z); o.w = f32_to_bf16(f.w);
    *(ushort4*)(dst + (long)which * 1048576 + base) = o;
}

extern "C" void kernel_launch(void* const* d_in, const int* in_sizes, int n_in,
                              void* d_out, int out_size, void* d_ws, size_t ws_size,
                              hipStream_t stream)
{
    const int B = 8, N = 2048, D = 1024;
    const long MT = (long)B * N;          // 16384
    const long nX = MT * D;               // 16,777,216
    const long nW = (long)D * D;          // 1,048,576

    const float* x  = (const float*)d_in[0];
    const float* Wq = (const float*)d_in[1];
    const float* Wk = (const float*)d_in[2];
    const float* Wv = (const float*)d_in[3];
    float* out = (float*)d_out;

    // ws layout (u16 units):
    u16* wb   = (u16*)d_ws;        // [3072][1024] stacked Wq;Wk;Wv; dead after qkv
    u16* xb   = wb + 3 * nW;       // [16384][1024] bf16 x
    u16* QKi  = xb + nX;           // [16384][2048] Q|K interleaved
    u16* Vt   = QKi + MT * 2048;   // [1024][16384] V transposed (written by qkv)
    u16* P    = Vt + nX;           // [8][2048][2048] exp(scores), unnormalized
    float* lsum = (float*)wb;      // alias: [8][2048] row sums (wb dead after qkv)

    // 1) fp32 -> bf16
    cvt_f32_bf16<<<(int)(nX / 1024), 256, 0, stream>>>(x, xb, nX);
    cvt_w3<<<3072, 256, 0, stream>>>(Wq, Wk, Wv, wb);

    // 2) fused QKV projection — 256^2 8-phase pipeline; V written transposed
    qkv_gemm8<<<dim3(768, 1, 1), 512, 0, stream>>>(xb, wb, QKi, Vt);

    // 3) zero row-sum accumulator (wb now dead)
    hipMemsetAsync(lsum, 0, (size_t)B * N * sizeof(float), stream);

    // 4) Ptilde = exp(Q.K^T/32) masked, + row sums — 8-phase 256^2, triangle.
    s_gemm8<<<dim3(288, 1, 1), 512, 0, stream>>>(QKi, P, lsum);

    // 5) O = Ptilde.V / lsum, K-limited. 128x256 tiles, LPT order.
    pv_gemm2<<<dim3(8, 4, 16), 512, 0, stream>>>(P, Vt, out, lsum);
}

// Round 5
// 350.038 us; speedup vs baseline: 1.0348x; 1.0348x over previous
//
#include <hip/hip_runtime.h>
#include <hip/hip_bf16.h>

typedef __attribute__((ext_vector_type(4))) float floatx4;
typedef __bf16 bf16x8 __attribute__((ext_vector_type(8)));
typedef unsigned int u32;
typedef unsigned short u16;

typedef __attribute__((address_space(1))) const u32 g_u32;
typedef __attribute__((address_space(3))) u32 l_u32;

__device__ __forceinline__ u16 f32_to_bf16(float f) {
    union { float f; u32 u; } x{f};
    u32 u = x.u;
    u32 r = (u + 0x7fffu + ((u >> 16) & 1u)) >> 16;
    return (u16)r;
}

// ============================================================================
// 8-phase 256x256 GEMM schedule (T1+T2+T3/T4+T5). Verified R2-R4:
// 0 bank conflicts, per-block T ~= 38.8 us at K=1024. LDS dest LINEAR
// (global_load_lds); T2 swizzle via pre-swizzled GLOBAL source col + swizzled
// ds_read (rule #21). Hazard schedule is iteration-invariant; ITERS may be a
// runtime value >= 1 (tiles = 2*ITERS, clamped tail prefetch re-stages the
// last tile with valid-but-unread data). vmcnt(4) coverage identical for all
// iteration counts (8 outstanding at P4/P8-end, wait-to-4 completes exactly
// the two half-tiles read next). DO NOT EDIT the barrier/vmcnt placement.
// ============================================================================

__device__ __forceinline__ void stage_half_sw(const u16* gbase, int ld, u16* lds_half, int tid) {
    int lane = tid & 63;
    int rsub = lane >> 3;                        // 0..7 row within 8-row slab
    int colsw = ((lane & 7) ^ rsub) << 3;        // swizzled source column (elems)
#pragma unroll
    for (int j = 0; j < 2; ++j) {
        int q = (tid >> 6) * 2 + j;              // 8-row slab index 0..15
        int row = q * 8 + rsub;
        const u16* g = gbase + (long)row * ld + colsw;
        u16* l = lds_half + q * 512 + lane * 8;  // linear: wave base + lane*16B
        __builtin_amdgcn_global_load_lds((g_u32*)g, (l_u32*)l, 16, 0, 0);
    }
}

// NT64 = number of 64-wide K-tiles = 2*ITERS. TMAX = NT64-1 (clamp).
#define EIGHT_PHASE_LOOP(Ab, Bb, lda, ldb, ITERS, TMAX)                                \
    stage_half_sw(Bb,                  ldb, &Bs[0][0],        tid);                    \
    stage_half_sw(Bb + 128 * (ldb),    ldb, &Bs[0][128 * 64], tid);                    \
    stage_half_sw(Ab,                  lda, &As[0][0],        tid);                    \
    stage_half_sw(Ab + 128 * (lda),    lda, &As[0][128 * 64], tid);                    \
    stage_half_sw(Bb + 64,             ldb, &Bs[1][0],        tid);                    \
    stage_half_sw(Bb + 64 + 128 * (ldb), ldb, &Bs[1][128 * 64], tid);                  \
    asm volatile("s_waitcnt vmcnt(4)" ::: "memory");                                   \
    __builtin_amdgcn_sched_barrier(0);                                                 \
    __builtin_amdgcn_s_barrier();                                                      \
    for (int i = 0; i < (ITERS); ++i) {                                                \
        int t1  = 2 * i + 1;                                                           \
        int tn  = (2 * i + 2 <= (TMAX)) ? 2 * i + 2 : (TMAX);                          \
        int tn1 = (2 * i + 3 <= (TMAX)) ? 2 * i + 3 : (TMAX);                          \
        const u16* gA1 = Ab + t1 * 64;                                                 \
        const u16* gB2 = Bb + tn * 64;                                                 \
        const u16* gA2 = Ab + tn * 64;                                                 \
        const u16* gB3 = Bb + tn1 * 64;                                                \
        bf16x8 bq0[4], bq1[4];                                                         \
        _Pragma("unroll")                                                              \
        for (int half = 0; half < 2; ++half) {                                         \
            _Pragma("unroll")                                                          \
            for (int p = 0; p < 4; ++p) {                                              \
                if (p == 0) {                                                          \
                    _Pragma("unroll")                                                  \
                    for (int ni = 0; ni < 4; ++ni) {                                   \
                        bq0[ni] = *(const bf16x8*)&Bs[half][brow + ni * 1024 + sl0];   \
                        bq1[ni] = *(const bf16x8*)&Bs[half][brow + ni * 1024 + sl1];   \
                    }                                                                  \
                }                                                                      \
                bf16x8 a00 = *(const bf16x8*)&As[half][arow + (2 * p)     * 1024 + sl0]; \
                bf16x8 a01 = *(const bf16x8*)&As[half][arow + (2 * p)     * 1024 + sl1]; \
                bf16x8 a10 = *(const bf16x8*)&As[half][arow + (2 * p + 1) * 1024 + sl0]; \
                bf16x8 a11 = *(const bf16x8*)&As[half][arow + (2 * p + 1) * 1024 + sl1]; \
                int ph = half * 4 + p;                                                 \
                switch (ph) {                                                          \
                    case 0: stage_half_sw(gA1,              lda, &As[1][0],        tid); break; \
                    case 1: stage_half_sw(gA1 + 128 * (lda), lda, &As[1][128 * 64], tid); break; \
                    case 2: stage_half_sw(gB2,              ldb, &Bs[0][0],        tid); break; \
                    case 3: stage_half_sw(gB2 + 128 * (ldb), ldb, &Bs[0][128 * 64], tid); break; \
                    case 4: stage_half_sw(gA2,              lda, &As[0][0],        tid); break; \
                    case 5: stage_half_sw(gA2 + 128 * (lda), lda, &As[0][128 * 64], tid); break; \
                    case 6: stage_half_sw(gB3,              ldb, &Bs[1][0],        tid); break; \
                    case 7: stage_half_sw(gB3 + 128 * (ldb), ldb, &Bs[1][128 * 64], tid); break; \
                }                                                                      \
                __builtin_amdgcn_s_barrier();                                          \
                __builtin_amdgcn_s_setprio(1);                                         \
                int m0 = 2 * p;                                                        \
                _Pragma("unroll")                                                      \
                for (int ni = 0; ni < 4; ++ni) {                                       \
                    acc[m0][ni]     = __builtin_amdgcn_mfma_f32_16x16x32_bf16(a00, bq0[ni], acc[m0][ni],     0, 0, 0); \
                    acc[m0][ni]     = __builtin_amdgcn_mfma_f32_16x16x32_bf16(a01, bq1[ni], acc[m0][ni],     0, 0, 0); \
                    acc[m0 + 1][ni] = __builtin_amdgcn_mfma_f32_16x16x32_bf16(a10, bq0[ni], acc[m0 + 1][ni], 0, 0, 0); \
                    acc[m0 + 1][ni] = __builtin_amdgcn_mfma_f32_16x16x32_bf16(a11, bq1[ni], acc[m0 + 1][ni], 0, 0, 0); \
                }                                                                      \
                __builtin_amdgcn_s_setprio(0);                                         \
                if (p == 3) {                                                          \
                    asm volatile("s_waitcnt vmcnt(4)" ::: "memory");                   \
                    __builtin_amdgcn_sched_barrier(0);                                 \
                }                                                                      \
                __builtin_amdgcn_s_barrier();                                          \
            }                                                                          \
        }                                                                              \
    }                                                                                  \
    asm volatile("s_waitcnt vmcnt(0)" ::: "memory");                                   \
    __builtin_amdgcn_sched_barrier(0);

// ============================================================================
// QKV projection (FROZEN since R3): C = X . Wstk^T, 768 blocks (3 rounds).
// Q,K -> QKi; V -> Vt transposed.
// ============================================================================
__global__ __launch_bounds__(512, 2)
void qkv_gemm8(const u16* __restrict__ A, const u16* __restrict__ Bw,
               u16* __restrict__ QKi, u16* __restrict__ Vt)
{
    __shared__ u16 As[2][256 * 64];
    __shared__ u16 Bs[2][256 * 64];

    int bid = blockIdx.x;
    int wg = (bid & 7) * 96 + (bid >> 3);
    int mt = wg / 12, nt = wg - mt * 12;

    int tid = threadIdx.x;
    int lane = tid & 63, wv = tid >> 6;
    int wr = wv >> 2, wc = wv & 3;
    int lrow = lane & 15, quad = lane >> 4;
    int sw = lrow & 7;

    const u16* Ab = A + (long)mt * 256 * 1024;
    const u16* Bb = Bw + (long)nt * 256 * 1024;

    floatx4 acc[8][4] = {};
    const int arow = (wr * 128 + lrow) * 64;
    const int brow = (wc * 64 + lrow) * 64;
    const int sl0 = (quad ^ sw) * 8;
    const int sl1 = ((4 + quad) ^ sw) * 8;

    EIGHT_PHASE_LOOP(Ab, Bb, 1024, 1024, 8, 15)

    if (nt < 8) {
        long crow0 = (long)mt * 256 + wr * 128 + quad * 4;
        int  ccol0 = nt * 256 + wc * 64 + lrow;
#pragma unroll
        for (int mi = 0; mi < 8; ++mi) {
#pragma unroll
            for (int r = 0; r < 4; ++r) {
                long row = crow0 + mi * 16 + r;
#pragma unroll
                for (int ni = 0; ni < 4; ++ni)
                    QKi[row * 2048 + ccol0 + ni * 16] = f32_to_bf16(acc[mi][ni][r]);
            }
        }
    } else {
        int dv0   = (nt - 8) * 256 + wc * 64 + lrow;
        long tok0 = (long)mt * 256 + wr * 128 + quad * 4;
#pragma unroll
        for (int mi = 0; mi < 8; ++mi) {
#pragma unroll
            for (int ni = 0; ni < 4; ++ni) {
                ushort4 o;
                o.x = f32_to_bf16(acc[mi][ni][0]);
                o.y = f32_to_bf16(acc[mi][ni][1]);
                o.z = f32_to_bf16(acc[mi][ni][2]);
                o.w = f32_to_bf16(acc[mi][ni][3]);
                *(ushort4*)(Vt + (long)(dv0 + ni * 16) * 16384 + tok0 + mi * 16) = o;
            }
        }
    }
}

// ============================================================================
// S kernel (FROZEN since R4): Ptilde = exp(Q.K^T/32), causal, rowsums.
// 288 blocks = 8 XCD x 36 triangle tiles.
// ============================================================================
__global__ __launch_bounds__(512, 2)
void s_gemm8(const u16* __restrict__ QKi, u16* __restrict__ P, float* __restrict__ lsum)
{
    __shared__ u16 As[2][256 * 64];
    __shared__ u16 Bs[2][256 * 64];

    int bid = blockIdx.x;                       // 0..287
    int b  = bid & 7;                           // batch == XCD slot
    int ti = bid >> 3;                          // 0..35 triangle index
    int mt = (int)((__builtin_sqrtf(8.0f * ti + 1.0f) - 1.0f) * 0.5f);
    while ((mt + 1) * (mt + 2) / 2 <= ti) ++mt; // fixup fp rounding
    while (mt * (mt + 1) / 2 > ti) --mt;
    int nt = ti - mt * (mt + 1) / 2;            // nt <= mt

    int tid = threadIdx.x;
    int lane = tid & 63, wv = tid >> 6;
    int wr = wv >> 2, wc = wv & 3;
    int lrow = lane & 15, quad = lane >> 4;
    int sw = lrow & 7;

    const u16* Qb = QKi + (long)b * 2048 * 2048 + (long)mt * 256 * 2048;        // Q rows
    const u16* Kb = QKi + (long)b * 2048 * 2048 + (long)nt * 256 * 2048 + 1024; // K rows
    u16* Pb = P + (long)b * 2048 * 2048;
    float* ls = lsum + b * 2048;

    floatx4 acc[8][4] = {};
    const int arow = (wr * 128 + lrow) * 64;
    const int brow = (wc * 64 + lrow) * 64;
    const int sl0 = (quad ^ sw) * 8;
    const int sl1 = ((4 + quad) ^ sw) * 8;

    EIGHT_PHASE_LOOP(Qb, Kb, 2048, 2048, 8, 15)

    int crow0 = mt * 256 + wr * 128 + quad * 4;
    int ccol0 = nt * 256 + wc * 64 + lrow;
#pragma unroll
    for (int mi = 0; mi < 8; ++mi) {
#pragma unroll
        for (int r = 0; r < 4; ++r) {
            int row = crow0 + mi * 16 + r;
            float rs = 0.f;
#pragma unroll
            for (int ni = 0; ni < 4; ++ni) {
                int col = ccol0 + ni * 16;
                float v = acc[mi][ni][r] * 0.03125f;
                float e = (col > row) ? 0.f : __expf(v);
                Pb[(long)row * 2048 + col] = f32_to_bf16(e);
                rs += e;
            }
            rs += __shfl_xor(rs, 1, 16);
            rs += __shfl_xor(rs, 2, 16);
            rs += __shfl_xor(rs, 4, 16);
            rs += __shfl_xor(rs, 8, 16);
            if (lrow == 0) atomicAdd(&ls[row], rs);
        }
    }
}

// ============================================================================
// PV, 8-phase 256x256 with variable K (trip-count generalization only):
// O[256 tok][256 dv] tile; A = P rows (lda 2048), B = Vt rows (ldb 16384).
// Causal K-limit: Keff = (mt+1)*256 -> iters = (mt+1)*2 in {2..16}.
// Grid 256 = 8 b x 8 mt x 4 nt -> exactly 1 block/CU, 1 round; wall = T(K=2048).
// ============================================================================
__global__ __launch_bounds__(512, 2)
void pv_gemm8(const u16* __restrict__ P, const u16* __restrict__ Vt,
              float* __restrict__ O, const float* __restrict__ lsum)
{
    __shared__ u16 As[2][256 * 64];
    __shared__ u16 Bs[2][256 * 64];

    int bid = blockIdx.x;            // 0..255
    int b  = bid & 7;                // batch == XCD slot (P,Vt panels L2-local)
    int r2 = bid >> 3;               // 0..31
    int mt = r2 >> 2;                // 0..7 token-row tile
    int nt = r2 & 3;                 // 0..3 dv-col tile

    int tid = threadIdx.x;
    int lane = tid & 63, wv = tid >> 6;
    int wr = wv >> 2, wc = wv & 3;
    int lrow = lane & 15, quad = lane >> 4;
    int sw = lrow & 7;

    const u16* Ab = P  + (long)b * 2048 * 2048 + (long)mt * 256 * 2048;  // lda 2048
    const u16* Bb = Vt + (long)nt * 256 * 16384 + b * 2048;              // ldb 16384
    float* Ob = O + (long)b * 2048 * 1024;
    const float* ls = lsum + b * 2048;

    int iters = (mt + 1) * 2;        // K-64 tiles = 2*iters
    int tmax  = (mt + 1) * 4 - 1;

    floatx4 acc[8][4] = {};
    const int arow = (wr * 128 + lrow) * 64;
    const int brow = (wc * 64 + lrow) * 64;
    const int sl0 = (quad ^ sw) * 8;
    const int sl1 = ((4 + quad) ^ sw) * 8;

    EIGHT_PHASE_LOOP(Ab, Bb, 2048, 16384, iters, tmax)

    // Epilogue: O = acc / lsum[row], fp32.
    int crow0 = mt * 256 + wr * 128 + quad * 4;
    int ccol0 = nt * 256 + wc * 64 + lrow;
#pragma unroll
    for (int mi = 0; mi < 8; ++mi) {
#pragma unroll
        for (int r = 0; r < 4; ++r) {
            int row = crow0 + mi * 16 + r;
            float linv = 1.0f / ls[row];
#pragma unroll
            for (int ni = 0; ni < 4; ++ni)
                Ob[(long)row * 1024 + ccol0 + ni * 16] = acc[mi][ni][r] * linv;
        }
    }
}

// ============================================================================
// Fused prep: x->bf16 (16384 blocks), W3->bf16 (3072 blocks), lsum=0 (16).
// Single launch replaces cvt_f32_bf16 + cvt_w3 + hipMemsetAsync.
// ============================================================================
__global__ __launch_bounds__(256)
void cvt_all(const float* __restrict__ x, const float* __restrict__ Wq,
             const float* __restrict__ Wk, const float* __restrict__ Wv,
             u16* __restrict__ xb, u16* __restrict__ wb, float* __restrict__ lsum)
{
    int bb = blockIdx.x;
    if (bb < 16384) {
        long idx = ((long)bb * 256 + threadIdx.x) << 2;
        float4 f = *(const float4*)(x + idx);
        ushort4 o;
        o.x = f32_to_bf16(f.x); o.y = f32_to_bf16(f.y);
        o.z = f32_to_bf16(f.z); o.w = f32_to_bf16(f.w);
        *(ushort4*)(xb + idx) = o;
    } else if (bb < 16384 + 3072) {
        int wbk = bb - 16384;
        int which = wbk >> 10;
        const float* src = which == 0 ? Wq : (which == 1 ? Wk : Wv);
        long base = (long)(wbk & 1023) * 1024 + threadIdx.x * 4;
        float4 f = *(const float4*)(src + base);
        ushort4 o;
        o.x = f32_to_bf16(f.x); o.y = f32_to_bf16(f.y);
        o.z = f32_to_bf16(f.z); o.w = f32_to_bf16(f.w);
        *(ushort4*)(wb + (long)which * 1048576 + base) = o;
    } else {
        long idx = ((long)(bb - 16384 - 3072) * 256 + threadIdx.x) << 2;
        *(float4*)(lsum + idx) = float4{0.f, 0.f, 0.f, 0.f};
    }
}

extern "C" void kernel_launch(void* const* d_in, const int* in_sizes, int n_in,
                              void* d_out, int out_size, void* d_ws, size_t ws_size,
                              hipStream_t stream)
{
    const int B = 8, N = 2048, D = 1024;
    const long MT = (long)B * N;          // 16384
    const long nX = MT * D;               // 16,777,216
    const long nW = (long)D * D;          // 1,048,576

    const float* x  = (const float*)d_in[0];
    const float* Wq = (const float*)d_in[1];
    const float* Wk = (const float*)d_in[2];
    const float* Wv = (const float*)d_in[3];
    float* out = (float*)d_out;

    // ws layout (u16 units):
    u16* wb   = (u16*)d_ws;        // [3072][1024] stacked Wq;Wk;Wv
    u16* xb   = wb + 3 * nW;       // [16384][1024] bf16 x
    u16* QKi  = xb + nX;           // [16384][2048] Q|K interleaved
    u16* Vt   = QKi + MT * 2048;   // [1024][16384] V transposed (written by qkv)
    u16* P    = Vt + nX;           // [8][2048][2048] exp(scores), unnormalized
    float* lsum = (float*)(P + (long)B * N * N);  // [8][2048] row sums (own region)

    // 1) fp32 -> bf16 (x + weights) and zero lsum — one launch
    cvt_all<<<16384 + 3072 + 16, 256, 0, stream>>>(x, Wq, Wk, Wv, xb, wb, lsum);

    // 2) fused QKV projection — 256^2 8-phase; V written transposed
    qkv_gemm8<<<dim3(768, 1, 1), 512, 0, stream>>>(xb, wb, QKi, Vt);

    // 3) Ptilde = exp(Q.K^T/32) masked, + row sums — 8-phase, triangle
    s_gemm8<<<dim3(288, 1, 1), 512, 0, stream>>>(QKi, P, lsum);

    // 4) O = Ptilde.V / lsum — 8-phase variable-K, 256 blocks (1 round)
    pv_gemm8<<<dim3(256, 1, 1), 512, 0, stream>>>(P, Vt, out, lsum);
}